// Round 1
// baseline (4027.439 us; speedup 1.0000x reference)
//
#include <hip/hip_runtime.h>
#include <math.h>

#define B_ 32
#define T_ 2048
#define E_ 1024
#define D_ 1024
#define H_ 4
#define DK_ 512
#define DV_ 512
#define C_ 10
#define FILT_ 100
#define KW_ 201
#define SCALING_ 2.0f

__device__ __forceinline__ float fast_tanh(float x) {
    x = fminf(15.f, fmaxf(-15.f, x));
    float e = __expf(2.f * x);
    return (e - 1.f) / (e + 1.f);
}

// ---------------- K1: q[b,h,dk] = dec_z[b,:] @ Wq[h,:,dk] + bq[h,dk] ----------------
__global__ __launch_bounds__(256) void qproj_kernel(
    const float* __restrict__ dec_z, const float* __restrict__ Wq,
    const float* __restrict__ bq, float* __restrict__ q) {
  int idx = blockIdx.x * 256 + threadIdx.x;   // B*H*DK
  int dk = idx & (DK_ - 1);
  int h  = (idx >> 9) & (H_ - 1);
  int b  = idx >> 11;
  const float* dz = dec_z + (size_t)b * D_;
  const float* w  = Wq + (size_t)h * D_ * DK_ + dk;
  float s = bq[h * DK_ + dk];
  for (int d = 0; d < D_; ++d) s += dz[d] * w[(size_t)d * DK_];
  q[idx] = s;
}

// ---------------- K2a: transpose conv_w (H,C,K) -> (H,K,C) for contiguous uniform loads
__global__ __launch_bounds__(256) void cwt_kernel(
    const float* __restrict__ cw, float* __restrict__ cwT) {
  int idx = blockIdx.x * 256 + threadIdx.x;
  if (idx < H_ * C_ * KW_) {
    int k = idx % KW_;
    int c = (idx / KW_) % C_;
    int h = idx / (KW_ * C_);
    cwT[((size_t)h * KW_ + k) * C_ + c] = cw[idx];
  }
}

// ---------------- K2b: conv_out[b,h,c,t] = sum_k cwT[h,k,c] * att_prev[b,h,t-FILT+k]
__global__ __launch_bounds__(256) void conv_kernel(
    const float* __restrict__ att_prev, const float* __restrict__ cwT,
    float* __restrict__ conv_out) {
  int bh = blockIdx.y;                 // b*H + h
  int h  = bh & (H_ - 1);
  int t0 = blockIdx.x * 256;
  int tid = threadIdx.x;
  __shared__ float sh[256 + 2 * FILT_];
  const float* ap = att_prev + (size_t)bh * T_;
  for (int f = tid; f < 256 + 2 * FILT_; f += 256) {
    int t = t0 + f - FILT_;
    sh[f] = (t >= 0 && t < T_) ? ap[t] : 0.f;
  }
  __syncthreads();
  const float* wt = cwT + (size_t)h * KW_ * C_;
  float out[C_];
#pragma unroll
  for (int c = 0; c < C_; ++c) out[c] = 0.f;
  for (int k = 0; k < KW_; ++k) {
    float x = sh[tid + k];
    const float* wk = wt + k * C_;     // uniform address -> scalar loads
#pragma unroll
    for (int c = 0; c < C_; ++c) out[c] += wk[c] * x;
  }
#pragma unroll
  for (int c = 0; c < C_; ++c)
    conv_out[((size_t)bh * C_ + c) * T_ + t0 + tid] = out[c];
}

// ---------------- K3: e[b,h,t] += sum_dk tanh(enc@Wk + loc + q) * gw  (the big one)
#define TT 128
#define TD 128
#define BK 16
__global__ __launch_bounds__(256) void e_gemm_kernel(
    const float* __restrict__ enc, const float* __restrict__ Wk,
    const float* __restrict__ q, const float* __restrict__ conv_out,
    const float* __restrict__ Watt, const float* __restrict__ gw,
    float* __restrict__ e_out) {
  __shared__ float smem[2 * BK * TT];      // 16 KiB, reused in epilogue
  float* Ast = smem;                       // [BK][TT]  (A transposed: k-major)
  float* Bs  = smem + BK * TT;             // [BK][TD]
  int tid = threadIdx.x;
  int tx = tid & 15, ty = tid >> 4;
  int bh = blockIdx.z;
  int b = bh >> 2, h = bh & 3;
  int t0  = blockIdx.y * TT;
  int dk0 = blockIdx.x * TD;
  const float* encb = enc + (size_t)b * T_ * E_;
  const float* Wkh  = Wk + (size_t)h * E_ * DK_;
  float acc[8][8];
#pragma unroll
  for (int i = 0; i < 8; ++i)
#pragma unroll
    for (int j = 0; j < 8; ++j) acc[i][j] = 0.f;

  for (int e0 = 0; e0 < E_; e0 += BK) {
#pragma unroll
    for (int l = 0; l < 2; ++l) {          // A tile: 128 rows x 16 cols
      int f = tid + l * 256;
      int r = f >> 2, c4 = (f & 3) * 4;
      const float4 a = *(const float4*)(encb + (size_t)(t0 + r) * E_ + e0 + c4);
      Ast[(c4 + 0) * TT + r] = a.x;
      Ast[(c4 + 1) * TT + r] = a.y;
      Ast[(c4 + 2) * TT + r] = a.z;
      Ast[(c4 + 3) * TT + r] = a.w;
    }
#pragma unroll
    for (int l = 0; l < 2; ++l) {          // B tile: 16 rows x 128 cols
      int f = tid + l * 256;
      int r = f >> 5, c4 = (f & 31) * 4;
      *(float4*)(Bs + r * TD + c4) =
          *(const float4*)(Wkh + (size_t)(e0 + r) * DK_ + dk0 + c4);
    }
    __syncthreads();
#pragma unroll
    for (int kk = 0; kk < BK; ++kk) {
      float av[8], bv[8];
      *(float4*)(av)     = *(const float4*)(Ast + kk * TT + ty * 8);
      *(float4*)(av + 4) = *(const float4*)(Ast + kk * TT + ty * 8 + 4);
      *(float4*)(bv)     = *(const float4*)(Bs + kk * TD + tx * 8);
      *(float4*)(bv + 4) = *(const float4*)(Bs + kk * TD + tx * 8 + 4);
#pragma unroll
      for (int i = 0; i < 8; ++i)
#pragma unroll
        for (int j = 0; j < 8; ++j) acc[i][j] += av[i] * bv[j];
    }
    __syncthreads();
  }

  // epilogue: stage conv_out tile [C][TT] and Watt tile [C][TD] in reused LDS
  float* convS = smem;             // [C_][TT]
  float* wattS = smem + C_ * TT;   // [C_][TD]
  const float* cvbh  = conv_out + (size_t)bh * C_ * T_;
  const float* Watth = Watt + (size_t)h * C_ * DK_;
  for (int f = tid; f < C_ * TT; f += 256) {
    int c = f >> 7, r = f & 127;
    convS[c * TT + r] = cvbh[(size_t)c * T_ + t0 + r];
    wattS[c * TD + r] = Watth[(size_t)c * DK_ + dk0 + r];
  }
  __syncthreads();
  const float* qbh = q + (size_t)bh * DK_;
  const float* gwh = gw + (size_t)h * DK_;
  float qv8[8], gw8[8];
#pragma unroll
  for (int j = 0; j < 8; ++j) {
    int dk = dk0 + tx * 8 + j;
    qv8[j] = qbh[dk];
    gw8[j] = gwh[dk];
  }
#pragma unroll
  for (int i = 0; i < 8; ++i) {
    int r = ty * 8 + i;
    float co[C_];
#pragma unroll
    for (int c = 0; c < C_; ++c) co[c] = convS[c * TT + r];
    float part = 0.f;
#pragma unroll
    for (int j = 0; j < 8; ++j) {
      float loc = 0.f;
#pragma unroll
      for (int c = 0; c < C_; ++c) loc += co[c] * wattS[c * TD + tx * 8 + j];
      part += fast_tanh(acc[i][j] + qv8[j] + loc) * gw8[j];
    }
#pragma unroll
    for (int off = 8; off > 0; off >>= 1) part += __shfl_xor(part, off, 64);
    if (tx == 0) atomicAdd(e_out + (size_t)bh * T_ + t0 + r, part);
  }
}

// ---------------- K4: w = softmax(SCALING*(e+gb)) with length mask ----------------
__global__ __launch_bounds__(256) void softmax_kernel(
    const float* __restrict__ e, const float* __restrict__ gb,
    const int* __restrict__ len, float* __restrict__ w_out) {
  int bh = blockIdx.x;
  int b = bh >> 2, h = bh & 3;
  int tid = threadIdx.x;
  int L = len[b];
  const float* er = e + (size_t)bh * T_;
  float* wr = w_out + (size_t)bh * T_;
  float gbh = gb[h];
  __shared__ float redA[4], redB[4];
  float mx = -1e30f;
  for (int t = tid; t < T_; t += 256)
    if (t < L) mx = fmaxf(mx, er[t] + gbh);
#pragma unroll
  for (int off = 32; off > 0; off >>= 1) mx = fmaxf(mx, __shfl_xor(mx, off, 64));
  if ((tid & 63) == 0) redA[tid >> 6] = mx;
  __syncthreads();
  mx = fmaxf(fmaxf(redA[0], redA[1]), fmaxf(redA[2], redA[3]));
  float sum = 0.f;
  for (int t = tid; t < T_; t += 256)
    if (t < L) sum += __expf(SCALING_ * ((er[t] + gbh) - mx));
#pragma unroll
  for (int off = 32; off > 0; off >>= 1) sum += __shfl_xor(sum, off, 64);
  if ((tid & 63) == 0) redB[tid >> 6] = sum;
  __syncthreads();
  sum = redB[0] + redB[1] + redB[2] + redB[3];
  float inv = 1.f / sum;
  for (int t = tid; t < T_; t += 256)
    wr[t] = (t < L) ? __expf(SCALING_ * ((er[t] + gbh) - mx)) * inv : 0.f;
}

// ---------------- K5: we[b,h,e] += sum_t w[b,h,t] * enc[b,t,e] ----------------
#define TCH 256
__global__ __launch_bounds__(256) void wenc_kernel(
    const float* __restrict__ enc, const float* __restrict__ w,
    const int* __restrict__ len, float* __restrict__ we) {
  int b = blockIdx.y;
  int t0 = blockIdx.x * TCH;
  int L = len[b];
  if (t0 >= L) return;
  int tid = threadIdx.x;
  __shared__ float wS[H_ * TCH];
  const float* wb = w + (size_t)b * H_ * T_;
#pragma unroll
  for (int l = 0; l < H_; ++l)
    wS[l * TCH + tid] = wb[(size_t)l * T_ + t0 + tid];
  __syncthreads();
  const float4* encb = (const float4*)(enc + (size_t)b * T_ * E_);
  int tmax = min(TCH, L - t0);
  float4 a0 = {0.f, 0.f, 0.f, 0.f}, a1 = a0, a2 = a0, a3 = a0;
  for (int tt = 0; tt < tmax; ++tt) {
    float4 x = encb[(size_t)(t0 + tt) * (E_ / 4) + tid];
    float w0 = wS[tt], w1 = wS[TCH + tt], w2 = wS[2 * TCH + tt], w3 = wS[3 * TCH + tt];
    a0.x += w0 * x.x; a0.y += w0 * x.y; a0.z += w0 * x.z; a0.w += w0 * x.w;
    a1.x += w1 * x.x; a1.y += w1 * x.y; a1.z += w1 * x.z; a1.w += w1 * x.w;
    a2.x += w2 * x.x; a2.y += w2 * x.y; a2.z += w2 * x.z; a2.w += w2 * x.w;
    a3.x += w3 * x.x; a3.y += w3 * x.y; a3.z += w3 * x.z; a3.w += w3 * x.w;
  }
  float* p = we + (size_t)b * H_ * E_ + tid * 4;
  atomicAdd(p + 0 * E_ + 0, a0.x); atomicAdd(p + 0 * E_ + 1, a0.y);
  atomicAdd(p + 0 * E_ + 2, a0.z); atomicAdd(p + 0 * E_ + 3, a0.w);
  atomicAdd(p + 1 * E_ + 0, a1.x); atomicAdd(p + 1 * E_ + 1, a1.y);
  atomicAdd(p + 1 * E_ + 2, a1.z); atomicAdd(p + 1 * E_ + 3, a1.w);
  atomicAdd(p + 2 * E_ + 0, a2.x); atomicAdd(p + 2 * E_ + 1, a2.y);
  atomicAdd(p + 2 * E_ + 2, a2.z); atomicAdd(p + 2 * E_ + 3, a2.w);
  atomicAdd(p + 3 * E_ + 0, a3.x); atomicAdd(p + 3 * E_ + 1, a3.y);
  atomicAdd(p + 3 * E_ + 2, a3.z); atomicAdd(p + 3 * E_ + 3, a3.w);
}

// ---------------- K6a: ctx[b,h,dv] = we[b,h,:] @ Wv[h,:,dv] ----------------
__global__ __launch_bounds__(256) void ctx_kernel(
    const float* __restrict__ we, const float* __restrict__ Wv,
    float* __restrict__ ctx) {
  int idx = blockIdx.x * 256 + threadIdx.x;  // B*H*DV
  int dv = idx & (DV_ - 1);
  int bh = idx >> 9;
  int h = bh & 3;
  const float* weh = we + (size_t)bh * E_;
  const float* wvp = Wv + (size_t)h * E_ * DV_ + dv;
  float s = 0.f;
  for (int e = 0; e < E_; ++e) s += weh[e] * wvp[(size_t)e * DV_];
  ctx[idx] = s;
}

// ---------------- K6b: c[b,eo] = ctx_flat[b,:] @ Wo[:,eo] ----------------
__global__ __launch_bounds__(256) void out_kernel(
    const float* __restrict__ ctx, const float* __restrict__ Wo,
    float* __restrict__ c_out) {
  int eo = blockIdx.x * 256 + threadIdx.x;
  int b = blockIdx.y;
  const float* cb = ctx + (size_t)b * (H_ * DV_);
  const float* wp = Wo + eo;
  float s = 0.f;
  for (int i = 0; i < H_ * DV_; ++i) s += cb[i] * wp[(size_t)i * E_];
  c_out[(size_t)b * E_ + eo] = s;
}

extern "C" void kernel_launch(void* const* d_in, const int* in_sizes, int n_in,
                              void* d_out, int out_size, void* d_ws, size_t ws_size,
                              hipStream_t stream) {
  const float* enc  = (const float*)d_in[0];
  const int*   len  = (const int*)d_in[1];
  const float* decz = (const float*)d_in[2];
  const float* attp = (const float*)d_in[3];
  const float* Wq   = (const float*)d_in[4];
  const float* bq   = (const float*)d_in[5];
  const float* Wk   = (const float*)d_in[6];
  const float* Wv   = (const float*)d_in[7];
  const float* gw   = (const float*)d_in[8];
  const float* gb   = (const float*)d_in[9];
  const float* cw   = (const float*)d_in[10];
  const float* Watt = (const float*)d_in[11];
  const float* Wo   = (const float*)d_in[12];

  float* c_out = (float*)d_out;                       // (B,E)
  float* w_out = c_out + (size_t)B_ * E_;             // (B,H,T)

  float* q    = (float*)d_ws;                                  // B*H*DK
  float* conv = q    + (size_t)B_ * H_ * DK_;                  // B*H*C*T
  float* e    = conv + (size_t)B_ * H_ * C_ * T_;              // B*H*T
  float* we   = e    + (size_t)B_ * H_ * T_;                   // B*H*E
  float* ctx  = we   + (size_t)B_ * H_ * E_;                   // B*H*DV
  float* cwT  = ctx  + (size_t)B_ * H_ * DV_;                  // H*K*C

  hipMemsetAsync(e, 0, (size_t)B_ * H_ * T_ * sizeof(float), stream);
  hipMemsetAsync(we, 0, (size_t)B_ * H_ * E_ * sizeof(float), stream);

  qproj_kernel<<<B_ * H_ * DK_ / 256, 256, 0, stream>>>(decz, Wq, bq, q);
  cwt_kernel<<<(H_ * C_ * KW_ + 255) / 256, 256, 0, stream>>>(cw, cwT);
  conv_kernel<<<dim3(T_ / 256, B_ * H_), 256, 0, stream>>>(attp, cwT, conv);
  e_gemm_kernel<<<dim3(DK_ / TD, T_ / TT, B_ * H_), 256, 0, stream>>>(
      enc, Wk, q, conv, Watt, gw, e);
  softmax_kernel<<<B_ * H_, 256, 0, stream>>>(e, gb, len, w_out);
  wenc_kernel<<<dim3(T_ / TCH, B_), 256, 0, stream>>>(enc, w_out, len, we);
  ctx_kernel<<<B_ * H_ * DV_ / 256, 256, 0, stream>>>(we, Wv, ctx);
  out_kernel<<<dim3(E_ / 256, B_), 256, 0, stream>>>(ctx, Wo, c_out);
}

// Round 2
// 1235.189 us; speedup vs baseline: 3.2606x; 3.2606x over previous
//
#include <hip/hip_runtime.h>
#include <math.h>

#define B_ 32
#define T_ 2048
#define E_ 1024
#define D_ 1024
#define H_ 4
#define DK_ 512
#define DV_ 512
#define C_ 10
#define FILT_ 100
#define KW_ 201
#define SCALING_ 2.0f
#define KEXT_ 32   // extension K-block holding [conv(10) | 1 | zeros]

typedef __bf16 bf16_t;
typedef __bf16 bf16x8 __attribute__((ext_vector_type(8)));
typedef float f32x4 __attribute__((ext_vector_type(4)));

__device__ __forceinline__ float fast_tanh(float x) {
    x = fminf(15.f, fmaxf(-15.f, x));
    float e = __expf(2.f * x);
    return (e - 1.f) / (e + 1.f);
}

__device__ __forceinline__ void gload16(const void* g, void* l) {
  __builtin_amdgcn_global_load_lds(
      (const __attribute__((address_space(1))) void*)g,
      (__attribute__((address_space(3))) void*)l, 16, 0, 0);
}

// ---------------- P1: fp32 -> bf16 elementwise (enc) ----------------
__global__ __launch_bounds__(256) void tobf16_kernel(
    const float* __restrict__ in, bf16_t* __restrict__ out) {
  size_t i = ((size_t)blockIdx.x * 256 + threadIdx.x) * 8;
  float4 a = *(const float4*)(in + i);
  float4 b = *(const float4*)(in + i + 4);
  bf16x8 o;
  o[0] = (bf16_t)a.x; o[1] = (bf16_t)a.y; o[2] = (bf16_t)a.z; o[3] = (bf16_t)a.w;
  o[4] = (bf16_t)b.x; o[5] = (bf16_t)b.y; o[6] = (bf16_t)b.z; o[7] = (bf16_t)b.w;
  *(bf16x8*)(out + i) = o;
}

// ---------------- P2: WkT[h,dk,e] = (bf16)Wk[h,e,dk] (tiled transpose) ----------------
__global__ __launch_bounds__(256) void wkt_kernel(
    const float* __restrict__ Wk, bf16_t* __restrict__ WkT) {
  __shared__ float t[32][33];
  int h = blockIdx.z;
  int dk0 = blockIdx.x * 32, e0 = blockIdx.y * 32;
  int x = threadIdx.x & 31, y0 = threadIdx.x >> 5;
  for (int yy = 0; yy < 32; yy += 8) {
    int y = y0 + yy;
    t[y][x] = Wk[((size_t)h * E_ + e0 + y) * DK_ + dk0 + x];
  }
  __syncthreads();
  for (int yy = 0; yy < 32; yy += 8) {
    int y = y0 + yy;
    WkT[((size_t)h * DK_ + dk0 + y) * E_ + e0 + x] = (bf16_t)t[x][y];
  }
}

// ---------------- K1: q[b,h,dk] = dec_z[b,:] @ Wq[h,:,dk] + bq[h,dk] ----------------
__global__ __launch_bounds__(256) void qproj_kernel(
    const float* __restrict__ dec_z, const float* __restrict__ Wq,
    const float* __restrict__ bq, float* __restrict__ q) {
  int idx = blockIdx.x * 256 + threadIdx.x;   // B*H*DK
  int dk = idx & (DK_ - 1);
  int h  = (idx >> 9) & (H_ - 1);
  int b  = idx >> 11;
  const float* dz = dec_z + (size_t)b * D_;
  const float* w  = Wq + (size_t)h * D_ * DK_ + dk;
  float s = bq[h * DK_ + dk];
  for (int d = 0; d < D_; ++d) s += dz[d] * w[(size_t)d * DK_];
  q[idx] = s;
}

// ---------------- P3: transpose conv_w (H,C,K) -> (H,K,C) ----------------
__global__ __launch_bounds__(256) void cwt_kernel(
    const float* __restrict__ cw, float* __restrict__ cwT) {
  int idx = blockIdx.x * 256 + threadIdx.x;
  if (idx < H_ * C_ * KW_) {
    int k = idx % KW_;
    int c = (idx / KW_) % C_;
    int h = idx / (KW_ * C_);
    cwT[((size_t)h * KW_ + k) * C_ + c] = cw[idx];
  }
}

// ---------------- K2: conv -> convT[bh,t,0:32] = [conv_c(t) x10 | 1 | zeros] bf16 ----
__global__ __launch_bounds__(256) void conv_kernel(
    const float* __restrict__ att_prev, const float* __restrict__ cwT,
    bf16_t* __restrict__ convT) {
  int bh = blockIdx.y;                 // b*H + h
  int h  = bh & (H_ - 1);
  int t0 = blockIdx.x * 256;
  int tid = threadIdx.x;
  __shared__ float sh[256 + 2 * FILT_];
  const float* ap = att_prev + (size_t)bh * T_;
  for (int f = tid; f < 256 + 2 * FILT_; f += 256) {
    int t = t0 + f - FILT_;
    sh[f] = (t >= 0 && t < T_) ? ap[t] : 0.f;
  }
  __syncthreads();
  const float* wt = cwT + (size_t)h * KW_ * C_;
  float out[C_];
#pragma unroll
  for (int c = 0; c < C_; ++c) out[c] = 0.f;
  for (int k = 0; k < KW_; ++k) {
    float x = sh[tid + k];
    const float* wk = wt + k * C_;     // uniform address -> scalar loads
#pragma unroll
    for (int c = 0; c < C_; ++c) out[c] += wk[c] * x;
  }
  bf16_t* o = convT + ((size_t)bh * T_ + t0 + tid) * KEXT_;
#pragma unroll
  for (int c = 0; c < C_; ++c) o[c] = (bf16_t)out[c];
  o[C_] = (bf16_t)1.0f;
#pragma unroll
  for (int c = C_ + 1; c < KEXT_; ++c) o[c] = (bf16_t)0.0f;
}

// ---------------- K3: Bext[bh,dk,0:32] = [Watt_c(dk) x10 | q(bh,dk) | zeros] bf16 ----
__global__ __launch_bounds__(256) void bext_kernel(
    const float* __restrict__ Watt, const float* __restrict__ q,
    bf16_t* __restrict__ Bext) {
  int idx = blockIdx.x * 256 + threadIdx.x;  // B*H*DK
  int dk = idx & (DK_ - 1);
  int h = (idx >> 9) & (H_ - 1);
  bf16_t* o = Bext + (size_t)idx * KEXT_;
#pragma unroll
  for (int c = 0; c < C_; ++c) o[c] = (bf16_t)Watt[((size_t)h * C_ + c) * DK_ + dk];
  o[C_] = (bf16_t)q[idx];
#pragma unroll
  for (int c = C_ + 1; c < KEXT_; ++c) o[c] = (bf16_t)0.0f;
}

// ---------------- K4: MFMA e-kernel: e[bh,t] = sum_dk tanh(enc@Wk + loc + q)*gw -----
// 128x128 tile, BK=64 bf16, global_load_lds 16B, 4 waves x (4x4) 16x16x32 MFMAs.
#define WT 128
#define WN 128
#define WKB 64
__global__ __launch_bounds__(256) void e_mfma_kernel(
    const bf16_t* __restrict__ encb, const bf16_t* __restrict__ WkT,
    const bf16_t* __restrict__ convT, const bf16_t* __restrict__ Bext,
    const float* __restrict__ gw, float* __restrict__ e_out) {
  __shared__ bf16_t As[WT * WKB];   // 16 KiB
  __shared__ bf16_t Bs[WN * WKB];   // 16 KiB
  int tid = threadIdx.x;
  int wave = tid >> 6, lane = tid & 63;
  int bh = blockIdx.z;
  int b = bh >> 2, h = bh & 3;
  int t0 = blockIdx.y * WT;
  int n0b = blockIdx.x * WN;
  const bf16_t* Ag = encb + ((size_t)b * T_ + t0) * E_;
  const bf16_t* Bg = WkT + ((size_t)h * DK_ + n0b) * E_;

  f32x4 acc[4][4] = {};

  int m0 = (wave & 1) * 64, n0 = (wave >> 1) * 64;
  int lr = lane & 15, lk = (lane >> 4) * 8;
  // staging indices (64-wide K-block): 8 rows per instr per wave
  int srow = wave * 32 + (lane >> 3);
  int scol = (lane & 7) * 8;

  for (int e0 = 0; e0 < E_; e0 += WKB) {
#pragma unroll
    for (int j = 0; j < 4; ++j) {
      int r = srow + j * 8;
      gload16(Ag + (size_t)r * E_ + e0 + scol, As + r * WKB + scol);
      gload16(Bg + (size_t)r * E_ + e0 + scol, Bs + r * WKB + scol);
    }
    __syncthreads();
#pragma unroll
    for (int kk = 0; kk < WKB; kk += 32) {
      bf16x8 af[4], bfv[4];
#pragma unroll
      for (int i = 0; i < 4; ++i) {
        af[i]  = *(const bf16x8*)(As + (m0 + i * 16 + lr) * WKB + kk + lk);
        bfv[i] = *(const bf16x8*)(Bs + (n0 + i * 16 + lr) * WKB + kk + lk);
      }
#pragma unroll
      for (int i = 0; i < 4; ++i)
#pragma unroll
        for (int j = 0; j < 4; ++j)
          acc[i][j] = __builtin_amdgcn_mfma_f32_16x16x32_bf16(
              af[i], bfv[j], acc[i][j], 0, 0, 0);
    }
    __syncthreads();
  }

  // extension K-block (32 wide): A <- convT rows, B <- Bext rows
  {
    const bf16_t* Ag2 = convT + ((size_t)bh * T_ + t0) * KEXT_;
    const bf16_t* Bg2 = Bext + ((size_t)bh * DK_ + n0b) * KEXT_;
    int srow2 = wave * 32 + (lane >> 2);   // 16 rows per instr per wave
    int scol2 = (lane & 3) * 8;
#pragma unroll
    for (int j = 0; j < 2; ++j) {
      int r = srow2 + j * 16;
      gload16(Ag2 + (size_t)r * KEXT_ + scol2, As + r * KEXT_ + scol2);
      gload16(Bg2 + (size_t)r * KEXT_ + scol2, Bs + r * KEXT_ + scol2);
    }
    __syncthreads();
    bf16x8 af[4], bfv[4];
#pragma unroll
    for (int i = 0; i < 4; ++i) {
      af[i]  = *(const bf16x8*)(As + (m0 + i * 16 + lr) * KEXT_ + lk);
      bfv[i] = *(const bf16x8*)(Bs + (n0 + i * 16 + lr) * KEXT_ + lk);
    }
#pragma unroll
    for (int i = 0; i < 4; ++i)
#pragma unroll
      for (int j = 0; j < 4; ++j)
        acc[i][j] = __builtin_amdgcn_mfma_f32_16x16x32_bf16(
            af[i], bfv[j], acc[i][j], 0, 0, 0);
  }

  // epilogue: e[t] partial = sum over this block's 128 dk cols of tanh(acc)*gw
  float gwv[4];
#pragma unroll
  for (int j = 0; j < 4; ++j)
    gwv[j] = gw[(size_t)h * DK_ + n0b + n0 + j * 16 + lr];
  int rquad = (lane >> 4) * 4;
#pragma unroll
  for (int i = 0; i < 4; ++i) {
#pragma unroll
    for (int r = 0; r < 4; ++r) {
      int row = m0 + i * 16 + rquad + r;
      float part = 0.f;
#pragma unroll
      for (int j = 0; j < 4; ++j)
        part += fast_tanh(acc[i][j][r]) * gwv[j];
#pragma unroll
      for (int off = 8; off > 0; off >>= 1) part += __shfl_xor(part, off, 64);
      if (lr == 0) atomicAdd(e_out + (size_t)bh * T_ + t0 + row, part);
    }
  }
}

// ---------------- K5: w = softmax(SCALING*(e+gb)) with length mask ----------------
__global__ __launch_bounds__(256) void softmax_kernel(
    const float* __restrict__ e, const float* __restrict__ gb,
    const int* __restrict__ len, float* __restrict__ w_out) {
  int bh = blockIdx.x;
  int b = bh >> 2, h = bh & 3;
  int tid = threadIdx.x;
  int L = len[b];
  const float* er = e + (size_t)bh * T_;
  float* wr = w_out + (size_t)bh * T_;
  float gbh = gb[h];
  __shared__ float redA[4], redB[4];
  float mx = -1e30f;
  for (int t = tid; t < T_; t += 256)
    if (t < L) mx = fmaxf(mx, er[t] + gbh);
#pragma unroll
  for (int off = 32; off > 0; off >>= 1) mx = fmaxf(mx, __shfl_xor(mx, off, 64));
  if ((tid & 63) == 0) redA[tid >> 6] = mx;
  __syncthreads();
  mx = fmaxf(fmaxf(redA[0], redA[1]), fmaxf(redA[2], redA[3]));
  float sum = 0.f;
  for (int t = tid; t < T_; t += 256)
    if (t < L) sum += __expf(SCALING_ * ((er[t] + gbh) - mx));
#pragma unroll
  for (int off = 32; off > 0; off >>= 1) sum += __shfl_xor(sum, off, 64);
  if ((tid & 63) == 0) redB[tid >> 6] = sum;
  __syncthreads();
  sum = redB[0] + redB[1] + redB[2] + redB[3];
  float inv = 1.f / sum;
  for (int t = tid; t < T_; t += 256)
    wr[t] = (t < L) ? __expf(SCALING_ * ((er[t] + gbh) - mx)) * inv : 0.f;
}

// ---------------- K6: we[b,h,e] += sum_t w[b,h,t] * enc[b,t,e] ----------------
#define TCH 256
__global__ __launch_bounds__(256) void wenc_kernel(
    const float* __restrict__ enc, const float* __restrict__ w,
    const int* __restrict__ len, float* __restrict__ we) {
  int b = blockIdx.y;
  int t0 = blockIdx.x * TCH;
  int L = len[b];
  if (t0 >= L) return;
  int tid = threadIdx.x;
  __shared__ float wS[H_ * TCH];
  const float* wb = w + (size_t)b * H_ * T_;
#pragma unroll
  for (int l = 0; l < H_; ++l)
    wS[l * TCH + tid] = wb[(size_t)l * T_ + t0 + tid];
  __syncthreads();
  const float4* encb = (const float4*)(enc + (size_t)b * T_ * E_);
  int tmax = min(TCH, L - t0);
  float4 a0 = {0.f, 0.f, 0.f, 0.f}, a1 = a0, a2 = a0, a3 = a0;
  for (int tt = 0; tt < tmax; ++tt) {
    float4 x = encb[(size_t)(t0 + tt) * (E_ / 4) + tid];
    float w0 = wS[tt], w1 = wS[TCH + tt], w2 = wS[2 * TCH + tt], w3 = wS[3 * TCH + tt];
    a0.x += w0 * x.x; a0.y += w0 * x.y; a0.z += w0 * x.z; a0.w += w0 * x.w;
    a1.x += w1 * x.x; a1.y += w1 * x.y; a1.z += w1 * x.z; a1.w += w1 * x.w;
    a2.x += w2 * x.x; a2.y += w2 * x.y; a2.z += w2 * x.z; a2.w += w2 * x.w;
    a3.x += w3 * x.x; a3.y += w3 * x.y; a3.z += w3 * x.z; a3.w += w3 * x.w;
  }
  float* p = we + (size_t)b * H_ * E_ + tid * 4;
  atomicAdd(p + 0 * E_ + 0, a0.x); atomicAdd(p + 0 * E_ + 1, a0.y);
  atomicAdd(p + 0 * E_ + 2, a0.z); atomicAdd(p + 0 * E_ + 3, a0.w);
  atomicAdd(p + 1 * E_ + 0, a1.x); atomicAdd(p + 1 * E_ + 1, a1.y);
  atomicAdd(p + 1 * E_ + 2, a1.z); atomicAdd(p + 1 * E_ + 3, a1.w);
  atomicAdd(p + 2 * E_ + 0, a2.x); atomicAdd(p + 2 * E_ + 1, a2.y);
  atomicAdd(p + 2 * E_ + 2, a2.z); atomicAdd(p + 2 * E_ + 3, a2.w);
  atomicAdd(p + 3 * E_ + 0, a3.x); atomicAdd(p + 3 * E_ + 1, a3.y);
  atomicAdd(p + 3 * E_ + 2, a3.z); atomicAdd(p + 3 * E_ + 3, a3.w);
}

// ---------------- K7a: ctx[b,h,dv] = we[b,h,:] @ Wv[h,:,dv] ----------------
__global__ __launch_bounds__(256) void ctx_kernel(
    const float* __restrict__ we, const float* __restrict__ Wv,
    float* __restrict__ ctx) {
  int idx = blockIdx.x * 256 + threadIdx.x;  // B*H*DV
  int dv = idx & (DV_ - 1);
  int bh = idx >> 9;
  int h = bh & 3;
  const float* weh = we + (size_t)bh * E_;
  const float* wvp = Wv + (size_t)h * E_ * DV_ + dv;
  float s = 0.f;
  for (int e = 0; e < E_; ++e) s += weh[e] * wvp[(size_t)e * DV_];
  ctx[idx] = s;
}

// ---------------- K7b: c[b,eo] = ctx_flat[b,:] @ Wo[:,eo] ----------------
__global__ __launch_bounds__(256) void out_kernel(
    const float* __restrict__ ctx, const float* __restrict__ Wo,
    float* __restrict__ c_out) {
  int eo = blockIdx.x * 256 + threadIdx.x;
  int b = blockIdx.y;
  const float* cb = ctx + (size_t)b * (H_ * DV_);
  const float* wp = Wo + eo;
  float s = 0.f;
  for (int i = 0; i < H_ * DV_; ++i) s += cb[i] * wp[(size_t)i * E_];
  c_out[(size_t)b * E_ + eo] = s;
}

extern "C" void kernel_launch(void* const* d_in, const int* in_sizes, int n_in,
                              void* d_out, int out_size, void* d_ws, size_t ws_size,
                              hipStream_t stream) {
  const float* enc  = (const float*)d_in[0];
  const int*   len  = (const int*)d_in[1];
  const float* decz = (const float*)d_in[2];
  const float* attp = (const float*)d_in[3];
  const float* Wq   = (const float*)d_in[4];
  const float* bq   = (const float*)d_in[5];
  const float* Wk   = (const float*)d_in[6];
  const float* Wv   = (const float*)d_in[7];
  const float* gw   = (const float*)d_in[8];
  const float* gb   = (const float*)d_in[9];
  const float* cw   = (const float*)d_in[10];
  const float* Watt = (const float*)d_in[11];
  const float* Wo   = (const float*)d_in[12];

  float* c_out = (float*)d_out;                       // (B,E)
  float* w_out = c_out + (size_t)B_ * E_;             // (B,H,T)

  // workspace carve-up (fp32 region then bf16 region)
  float* q    = (float*)d_ws;                                   // B*H*DK
  float* e    = q   + (size_t)B_ * H_ * DK_;                    // B*H*T
  float* we   = e   + (size_t)B_ * H_ * T_;                     // B*H*E
  float* ctx  = we  + (size_t)B_ * H_ * E_;                     // B*H*DV
  float* cwT  = ctx + (size_t)B_ * H_ * DV_;                    // H*KW*C
  bf16_t* encb16 = (bf16_t*)(cwT + (size_t)H_ * KW_ * C_ + 64); // B*T*E
  bf16_t* WkT    = encb16 + (size_t)B_ * T_ * E_;               // H*DK*E
  bf16_t* convT  = WkT + (size_t)H_ * DK_ * E_;                 // B*H*T*KEXT
  bf16_t* Bext   = convT + (size_t)B_ * H_ * T_ * KEXT_;        // B*H*DK*KEXT

  hipMemsetAsync(e, 0, (size_t)B_ * H_ * T_ * sizeof(float), stream);
  hipMemsetAsync(we, 0, (size_t)B_ * H_ * E_ * sizeof(float), stream);

  tobf16_kernel<<<(size_t)B_ * T_ * E_ / 8 / 256, 256, 0, stream>>>(enc, encb16);
  wkt_kernel<<<dim3(DK_ / 32, E_ / 32, H_), 256, 0, stream>>>(Wk, WkT);
  qproj_kernel<<<B_ * H_ * DK_ / 256, 256, 0, stream>>>(decz, Wq, bq, q);
  cwt_kernel<<<(H_ * C_ * KW_ + 255) / 256, 256, 0, stream>>>(cw, cwT);
  conv_kernel<<<dim3(T_ / 256, B_ * H_), 256, 0, stream>>>(attp, cwT, convT);
  bext_kernel<<<B_ * H_ * DK_ / 256, 256, 0, stream>>>(Watt, q, Bext);
  e_mfma_kernel<<<dim3(DK_ / WN, T_ / WT, B_ * H_), 256, 0, stream>>>(
      encb16, WkT, convT, Bext, gw, e);
  softmax_kernel<<<B_ * H_, 256, 0, stream>>>(e, gb, len, w_out);
  wenc_kernel<<<dim3(T_ / TCH, B_), 256, 0, stream>>>(enc, w_out, len, we);
  ctx_kernel<<<B_ * H_ * DV_ / 256, 256, 0, stream>>>(we, Wv, ctx);
  out_kernel<<<dim3(E_ / 256, B_), 256, 0, stream>>>(ctx, Wo, c_out);
}

// Round 3
// 1108.143 us; speedup vs baseline: 3.6344x; 1.1146x over previous
//
#include <hip/hip_runtime.h>
#include <math.h>

#define B_ 32
#define T_ 2048
#define E_ 1024
#define D_ 1024
#define H_ 4
#define DK_ 512
#define DV_ 512
#define C_ 10
#define FILT_ 100
#define KW_ 201
#define SCALING_ 2.0f
#define KEXT_ 32   // extension K-block holding [conv(10) | 1 | zeros]

typedef __bf16 bf16_t;
typedef __bf16 bf16x8 __attribute__((ext_vector_type(8)));
typedef float f32x4 __attribute__((ext_vector_type(4)));

__device__ __forceinline__ float fast_tanh(float x) {
    x = fminf(15.f, fmaxf(-15.f, x));
    float e = __expf(2.f * x);
    return (e - 1.f) / (e + 1.f);
}

__device__ __forceinline__ void gload16(const void* g, void* l) {
  __builtin_amdgcn_global_load_lds(
      (const __attribute__((address_space(1))) void*)g,
      (__attribute__((address_space(3))) void*)l, 16, 0, 0);
}

// ---------------- P1: fp32 -> bf16 elementwise (enc) ----------------
__global__ __launch_bounds__(256) void tobf16_kernel(
    const float* __restrict__ in, bf16_t* __restrict__ out) {
  size_t i = ((size_t)blockIdx.x * 256 + threadIdx.x) * 8;
  float4 a = *(const float4*)(in + i);
  float4 b = *(const float4*)(in + i + 4);
  bf16x8 o;
  o[0] = (bf16_t)a.x; o[1] = (bf16_t)a.y; o[2] = (bf16_t)a.z; o[3] = (bf16_t)a.w;
  o[4] = (bf16_t)b.x; o[5] = (bf16_t)b.y; o[6] = (bf16_t)b.z; o[7] = (bf16_t)b.w;
  *(bf16x8*)(out + i) = o;
}

// ---------------- P2: WkT[h,dk,e] = (bf16)Wk[h,e,dk] (tiled transpose) ----------------
__global__ __launch_bounds__(256) void wkt_kernel(
    const float* __restrict__ Wk, bf16_t* __restrict__ WkT) {
  __shared__ float t[32][33];
  int h = blockIdx.z;
  int dk0 = blockIdx.x * 32, e0 = blockIdx.y * 32;
  int x = threadIdx.x & 31, y0 = threadIdx.x >> 5;
  for (int yy = 0; yy < 32; yy += 8) {
    int y = y0 + yy;
    t[y][x] = Wk[((size_t)h * E_ + e0 + y) * DK_ + dk0 + x];
  }
  __syncthreads();
  for (int yy = 0; yy < 32; yy += 8) {
    int y = y0 + yy;
    WkT[((size_t)h * DK_ + dk0 + y) * E_ + e0 + x] = (bf16_t)t[x][y];
  }
}

// ---------------- K1: q[b,h,dk] += partial(dec_z[b,:] @ Wq[h,:,dk]) + bq ----------------
#define QSPLIT 8
__global__ __launch_bounds__(256) void qproj_kernel(
    const float* __restrict__ dec_z, const float* __restrict__ Wq,
    const float* __restrict__ bq, float* __restrict__ q) {
  int idx = blockIdx.x * 256 + threadIdx.x;   // B*H*DK
  int s = blockIdx.y;
  int dk = idx & (DK_ - 1);
  int h  = (idx >> 9) & (H_ - 1);
  int b  = idx >> 11;
  const int CH = D_ / QSPLIT;                 // 128
  const float* dz = dec_z + (size_t)b * D_ + s * CH;
  const float* w  = Wq + (size_t)h * D_ * DK_ + (size_t)(s * CH) * DK_ + dk;
  float acc = (s == 0) ? bq[h * DK_ + dk] : 0.f;
  for (int d = 0; d < CH; ++d) acc += dz[d] * w[(size_t)d * DK_];
  atomicAdd(q + idx, acc);
}

// ---------------- P3: transpose conv_w (H,C,K) -> (H,K,C) ----------------
__global__ __launch_bounds__(256) void cwt_kernel(
    const float* __restrict__ cw, float* __restrict__ cwT) {
  int idx = blockIdx.x * 256 + threadIdx.x;
  if (idx < H_ * C_ * KW_) {
    int k = idx % KW_;
    int c = (idx / KW_) % C_;
    int h = idx / (KW_ * C_);
    cwT[((size_t)h * KW_ + k) * C_ + c] = cw[idx];
  }
}

// ---------------- K2: conv -> convT[bh,t,0:32] = [conv_c(t) x10 | 1 | zeros] bf16 ----
__global__ __launch_bounds__(256) void conv_kernel(
    const float* __restrict__ att_prev, const float* __restrict__ cwT,
    bf16_t* __restrict__ convT) {
  int bh = blockIdx.y;                 // b*H + h
  int h  = bh & (H_ - 1);
  int t0 = blockIdx.x * 256;
  int tid = threadIdx.x;
  __shared__ float sh[256 + 2 * FILT_];
  const float* ap = att_prev + (size_t)bh * T_;
  for (int f = tid; f < 256 + 2 * FILT_; f += 256) {
    int t = t0 + f - FILT_;
    sh[f] = (t >= 0 && t < T_) ? ap[t] : 0.f;
  }
  __syncthreads();
  const float* wt = cwT + (size_t)h * KW_ * C_;
  float out[C_];
#pragma unroll
  for (int c = 0; c < C_; ++c) out[c] = 0.f;
  for (int k = 0; k < KW_; ++k) {
    float x = sh[tid + k];
    const float* wk = wt + k * C_;     // uniform address -> scalar loads
#pragma unroll
    for (int c = 0; c < C_; ++c) out[c] += wk[c] * x;
  }
  bf16_t* o = convT + ((size_t)bh * T_ + t0 + tid) * KEXT_;
#pragma unroll
  for (int c = 0; c < C_; ++c) o[c] = (bf16_t)out[c];
  o[C_] = (bf16_t)1.0f;
#pragma unroll
  for (int c = C_ + 1; c < KEXT_; ++c) o[c] = (bf16_t)0.0f;
}

// ---------------- K3: Bext[bh,dk,0:32] = [Watt_c(dk) x10 | q(bh,dk) | zeros] bf16 ----
__global__ __launch_bounds__(256) void bext_kernel(
    const float* __restrict__ Watt, const float* __restrict__ q,
    bf16_t* __restrict__ Bext) {
  int idx = blockIdx.x * 256 + threadIdx.x;  // B*H*DK
  int dk = idx & (DK_ - 1);
  int h = (idx >> 9) & (H_ - 1);
  bf16_t* o = Bext + (size_t)idx * KEXT_;
#pragma unroll
  for (int c = 0; c < C_; ++c) o[c] = (bf16_t)Watt[((size_t)h * C_ + c) * DK_ + dk];
  o[C_] = (bf16_t)q[idx];
#pragma unroll
  for (int c = C_ + 1; c < KEXT_; ++c) o[c] = (bf16_t)0.0f;
}

// ---------------- K4: MFMA e-kernel: e[bh,t] = sum_dk tanh(enc@Wk + loc + q)*gw -----
// 128x128 tile, BK=64 bf16, global_load_lds 16B, XOR-swizzled LDS (conflict-free),
// 4 waves x (4x4) 16x16x32 MFMAs.
#define WT 128
#define WN 128
#define WKB 64
__global__ __launch_bounds__(256) void e_mfma_kernel(
    const bf16_t* __restrict__ encb, const bf16_t* __restrict__ WkT,
    const bf16_t* __restrict__ convT, const bf16_t* __restrict__ Bext,
    const float* __restrict__ gw, float* __restrict__ e_out) {
  __shared__ bf16_t As[WT * WKB];   // 16 KiB
  __shared__ bf16_t Bs[WN * WKB];   // 16 KiB
  int tid = threadIdx.x;
  int wave = tid >> 6, lane = tid & 63;
  int bh = blockIdx.z;
  int b = bh >> 2, h = bh & 3;
  int t0 = blockIdx.y * WT;
  int n0b = blockIdx.x * WN;
  const bf16_t* Ag = encb + ((size_t)b * T_ + t0) * E_;
  const bf16_t* Bg = WkT + ((size_t)h * DK_ + n0b) * E_;

  f32x4 acc[4][4] = {};

  int m0 = (wave & 1) * 64, n0 = (wave >> 1) * 64;
  int lr = lane & 15, lk = (lane >> 4) * 8;
  // staging indices (64-wide K-block): LDS slot (r, cb) <- global colblock cb^(r&7)
  int srow = wave * 32 + (lane >> 3);
  int cb   = lane & 7;

  for (int e0 = 0; e0 < E_; e0 += WKB) {
#pragma unroll
    for (int j = 0; j < 4; ++j) {
      int r = srow + j * 8;
      int gc = (cb ^ (r & 7)) * 8;
      gload16(Ag + (size_t)r * E_ + e0 + gc, As + r * WKB + cb * 8);
      gload16(Bg + (size_t)r * E_ + e0 + gc, Bs + r * WKB + cb * 8);
    }
    __syncthreads();
#pragma unroll
    for (int kk = 0; kk < WKB; kk += 32) {
      int sc = ((((kk + lk) >> 3) ^ (lr & 7)) << 3);  // swizzled col offset
      bf16x8 af[4], bfv[4];
#pragma unroll
      for (int i = 0; i < 4; ++i) {
        af[i]  = *(const bf16x8*)(As + (m0 + i * 16 + lr) * WKB + sc);
        bfv[i] = *(const bf16x8*)(Bs + (n0 + i * 16 + lr) * WKB + sc);
      }
#pragma unroll
      for (int i = 0; i < 4; ++i)
#pragma unroll
        for (int j = 0; j < 4; ++j)
          acc[i][j] = __builtin_amdgcn_mfma_f32_16x16x32_bf16(
              af[i], bfv[j], acc[i][j], 0, 0, 0);
    }
    __syncthreads();
  }

  // extension K-block (32 wide): A <- convT rows, B <- Bext rows (no swizzle; one-shot)
  {
    const bf16_t* Ag2 = convT + ((size_t)bh * T_ + t0) * KEXT_;
    const bf16_t* Bg2 = Bext + ((size_t)bh * DK_ + n0b) * KEXT_;
    int srow2 = wave * 32 + (lane >> 2);   // 16 rows per instr per wave
    int scol2 = (lane & 3) * 8;
#pragma unroll
    for (int j = 0; j < 2; ++j) {
      int r = srow2 + j * 16;
      gload16(Ag2 + (size_t)r * KEXT_ + scol2, As + r * KEXT_ + scol2);
      gload16(Bg2 + (size_t)r * KEXT_ + scol2, Bs + r * KEXT_ + scol2);
    }
    __syncthreads();
    bf16x8 af[4], bfv[4];
#pragma unroll
    for (int i = 0; i < 4; ++i) {
      af[i]  = *(const bf16x8*)(As + (m0 + i * 16 + lr) * KEXT_ + lk);
      bfv[i] = *(const bf16x8*)(Bs + (n0 + i * 16 + lr) * KEXT_ + lk);
    }
#pragma unroll
    for (int i = 0; i < 4; ++i)
#pragma unroll
      for (int j = 0; j < 4; ++j)
        acc[i][j] = __builtin_amdgcn_mfma_f32_16x16x32_bf16(
            af[i], bfv[j], acc[i][j], 0, 0, 0);
  }

  // epilogue: e[t] partial = sum over this block's 128 dk cols of tanh(acc)*gw
  float gwv[4];
#pragma unroll
  for (int j = 0; j < 4; ++j)
    gwv[j] = gw[(size_t)h * DK_ + n0b + n0 + j * 16 + lr];
  int rquad = (lane >> 4) * 4;
#pragma unroll
  for (int i = 0; i < 4; ++i) {
#pragma unroll
    for (int r = 0; r < 4; ++r) {
      int row = m0 + i * 16 + rquad + r;
      float part = 0.f;
#pragma unroll
      for (int j = 0; j < 4; ++j)
        part += fast_tanh(acc[i][j][r]) * gwv[j];
#pragma unroll
      for (int off = 8; off > 0; off >>= 1) part += __shfl_xor(part, off, 64);
      if (lr == 0) atomicAdd(e_out + (size_t)bh * T_ + t0 + row, part);
    }
  }
}

// ---------------- K5: w = softmax(SCALING*(e+gb)) with length mask ----------------
__global__ __launch_bounds__(256) void softmax_kernel(
    const float* __restrict__ e, const float* __restrict__ gb,
    const int* __restrict__ len, float* __restrict__ w_out) {
  int bh = blockIdx.x;
  int b = bh >> 2, h = bh & 3;
  int tid = threadIdx.x;
  int L = len[b];
  const float* er = e + (size_t)bh * T_;
  float* wr = w_out + (size_t)bh * T_;
  float gbh = gb[h];
  __shared__ float redA[4], redB[4];
  float mx = -1e30f;
  for (int t = tid; t < T_; t += 256)
    if (t < L) mx = fmaxf(mx, er[t] + gbh);
#pragma unroll
  for (int off = 32; off > 0; off >>= 1) mx = fmaxf(mx, __shfl_xor(mx, off, 64));
  if ((tid & 63) == 0) redA[tid >> 6] = mx;
  __syncthreads();
  mx = fmaxf(fmaxf(redA[0], redA[1]), fmaxf(redA[2], redA[3]));
  float sum = 0.f;
  for (int t = tid; t < T_; t += 256)
    if (t < L) sum += __expf(SCALING_ * ((er[t] + gbh) - mx));
#pragma unroll
  for (int off = 32; off > 0; off >>= 1) sum += __shfl_xor(sum, off, 64);
  if ((tid & 63) == 0) redB[tid >> 6] = sum;
  __syncthreads();
  sum = redB[0] + redB[1] + redB[2] + redB[3];
  float inv = 1.f / sum;
  for (int t = tid; t < T_; t += 256)
    wr[t] = (t < L) ? __expf(SCALING_ * ((er[t] + gbh) - mx)) * inv : 0.f;
}

// ---------------- K6: we[b,h,e] += sum_t w[b,h,t] * enc[b,t,e] ----------------
#define TCH 256
__global__ __launch_bounds__(256) void wenc_kernel(
    const float* __restrict__ enc, const float* __restrict__ w,
    const int* __restrict__ len, float* __restrict__ we) {
  int b = blockIdx.y;
  int t0 = blockIdx.x * TCH;
  int L = len[b];
  if (t0 >= L) return;
  int tid = threadIdx.x;
  __shared__ float wS[H_ * TCH];
  const float* wb = w + (size_t)b * H_ * T_;
#pragma unroll
  for (int l = 0; l < H_; ++l)
    wS[l * TCH + tid] = wb[(size_t)l * T_ + t0 + tid];
  __syncthreads();
  const float4* encb = (const float4*)(enc + (size_t)b * T_ * E_);
  int tmax = min(TCH, L - t0);
  float4 a0 = {0.f, 0.f, 0.f, 0.f}, a1 = a0, a2 = a0, a3 = a0;
  for (int tt = 0; tt < tmax; ++tt) {
    float4 x = encb[(size_t)(t0 + tt) * (E_ / 4) + tid];
    float w0 = wS[tt], w1 = wS[TCH + tt], w2 = wS[2 * TCH + tt], w3 = wS[3 * TCH + tt];
    a0.x += w0 * x.x; a0.y += w0 * x.y; a0.z += w0 * x.z; a0.w += w0 * x.w;
    a1.x += w1 * x.x; a1.y += w1 * x.y; a1.z += w1 * x.z; a1.w += w1 * x.w;
    a2.x += w2 * x.x; a2.y += w2 * x.y; a2.z += w2 * x.z; a2.w += w2 * x.w;
    a3.x += w3 * x.x; a3.y += w3 * x.y; a3.z += w3 * x.z; a3.w += w3 * x.w;
  }
  float* p = we + (size_t)b * H_ * E_ + tid * 4;
  atomicAdd(p + 0 * E_ + 0, a0.x); atomicAdd(p + 0 * E_ + 1, a0.y);
  atomicAdd(p + 0 * E_ + 2, a0.z); atomicAdd(p + 0 * E_ + 3, a0.w);
  atomicAdd(p + 1 * E_ + 0, a1.x); atomicAdd(p + 1 * E_ + 1, a1.y);
  atomicAdd(p + 1 * E_ + 2, a1.z); atomicAdd(p + 1 * E_ + 3, a1.w);
  atomicAdd(p + 2 * E_ + 0, a2.x); atomicAdd(p + 2 * E_ + 1, a2.y);
  atomicAdd(p + 2 * E_ + 2, a2.z); atomicAdd(p + 2 * E_ + 3, a2.w);
  atomicAdd(p + 3 * E_ + 0, a3.x); atomicAdd(p + 3 * E_ + 1, a3.y);
  atomicAdd(p + 3 * E_ + 2, a3.z); atomicAdd(p + 3 * E_ + 3, a3.w);
}

// ---------------- K7a: ctx[b,h,dv] += partial(we[b,h,:] @ Wv[h,:,dv]) ----------------
#define CSPLIT 8
__global__ __launch_bounds__(256) void ctx_kernel(
    const float* __restrict__ we, const float* __restrict__ Wv,
    float* __restrict__ ctx) {
  int idx = blockIdx.x * 256 + threadIdx.x;  // B*H*DV
  int s = blockIdx.y;
  int dv = idx & (DV_ - 1);
  int bh = idx >> 9;
  int h = bh & 3;
  const int CH = E_ / CSPLIT;                // 128
  const float* weh = we + (size_t)bh * E_ + s * CH;
  const float* wvp = Wv + (size_t)h * E_ * DV_ + (size_t)(s * CH) * DV_ + dv;
  float acc = 0.f;
  for (int e = 0; e < CH; ++e) acc += weh[e] * wvp[(size_t)e * DV_];
  atomicAdd(ctx + idx, acc);
}

// ---------------- K7b: c[b,eo] += partial(ctx_flat[b,:] @ Wo[:,eo]) ----------------
#define OSPLIT 8
__global__ __launch_bounds__(256) void out_kernel(
    const float* __restrict__ ctx, const float* __restrict__ Wo,
    float* __restrict__ c_out) {
  int eo = blockIdx.x * 256 + threadIdx.x;
  int b = blockIdx.y;
  int s = blockIdx.z;
  const int CH = (H_ * DV_) / OSPLIT;        // 256
  const float* cb = ctx + (size_t)b * (H_ * DV_) + s * CH;
  const float* wp = Wo + (size_t)(s * CH) * E_ + eo;
  float acc = 0.f;
  for (int i = 0; i < CH; ++i) acc += cb[i] * wp[(size_t)i * E_];
  atomicAdd(c_out + (size_t)b * E_ + eo, acc);
}

extern "C" void kernel_launch(void* const* d_in, const int* in_sizes, int n_in,
                              void* d_out, int out_size, void* d_ws, size_t ws_size,
                              hipStream_t stream) {
  const float* enc  = (const float*)d_in[0];
  const int*   len  = (const int*)d_in[1];
  const float* decz = (const float*)d_in[2];
  const float* attp = (const float*)d_in[3];
  const float* Wq   = (const float*)d_in[4];
  const float* bq   = (const float*)d_in[5];
  const float* Wk   = (const float*)d_in[6];
  const float* Wv   = (const float*)d_in[7];
  const float* gw   = (const float*)d_in[8];
  const float* gb   = (const float*)d_in[9];
  const float* cw   = (const float*)d_in[10];
  const float* Watt = (const float*)d_in[11];
  const float* Wo   = (const float*)d_in[12];

  float* c_out = (float*)d_out;                       // (B,E)
  float* w_out = c_out + (size_t)B_ * E_;             // (B,H,T)

  // workspace carve-up (fp32 region then bf16 region)
  float* q    = (float*)d_ws;                                   // B*H*DK
  float* e    = q   + (size_t)B_ * H_ * DK_;                    // B*H*T
  float* we   = e   + (size_t)B_ * H_ * T_;                     // B*H*E
  float* ctx  = we  + (size_t)B_ * H_ * E_;                     // B*H*DV
  float* cwT  = ctx + (size_t)B_ * H_ * DV_;                    // H*KW*C
  bf16_t* encb16 = (bf16_t*)(cwT + (size_t)H_ * KW_ * C_ + 64); // B*T*E
  bf16_t* WkT    = encb16 + (size_t)B_ * T_ * E_;               // H*DK*E
  bf16_t* convT  = WkT + (size_t)H_ * DK_ * E_;                 // B*H*T*KEXT
  bf16_t* Bext   = convT + (size_t)B_ * H_ * T_ * KEXT_;        // B*H*DK*KEXT

  hipMemsetAsync(q, 0, (size_t)B_ * H_ * DK_ * sizeof(float), stream);
  hipMemsetAsync(e, 0, (size_t)B_ * H_ * T_ * sizeof(float), stream);
  hipMemsetAsync(we, 0, (size_t)B_ * H_ * E_ * sizeof(float), stream);
  hipMemsetAsync(ctx, 0, (size_t)B_ * H_ * DV_ * sizeof(float), stream);
  hipMemsetAsync(c_out, 0, (size_t)B_ * E_ * sizeof(float), stream);

  tobf16_kernel<<<(size_t)B_ * T_ * E_ / 8 / 256, 256, 0, stream>>>(enc, encb16);
  wkt_kernel<<<dim3(DK_ / 32, E_ / 32, H_), 256, 0, stream>>>(Wk, WkT);
  qproj_kernel<<<dim3(B_ * H_ * DK_ / 256, QSPLIT), 256, 0, stream>>>(decz, Wq, bq, q);
  cwt_kernel<<<(H_ * C_ * KW_ + 255) / 256, 256, 0, stream>>>(cw, cwT);
  conv_kernel<<<dim3(T_ / 256, B_ * H_), 256, 0, stream>>>(attp, cwT, convT);
  bext_kernel<<<B_ * H_ * DK_ / 256, 256, 0, stream>>>(Watt, q, Bext);
  e_mfma_kernel<<<dim3(DK_ / WN, T_ / WT, B_ * H_), 256, 0, stream>>>(
      encb16, WkT, convT, Bext, gw, e);
  softmax_kernel<<<B_ * H_, 256, 0, stream>>>(e, gb, len, w_out);
  wenc_kernel<<<dim3(T_ / TCH, B_), 256, 0, stream>>>(enc, w_out, len, we);
  ctx_kernel<<<dim3(B_ * H_ * DV_ / 256, CSPLIT), 256, 0, stream>>>(we, Wv, ctx);
  out_kernel<<<dim3(E_ / 256, B_, OSPLIT), 256, 0, stream>>>(ctx, Wo, c_out);
}

// Round 4
// 994.905 us; speedup vs baseline: 4.0481x; 1.1138x over previous
//
#include <hip/hip_runtime.h>
#include <math.h>

#define B_ 32
#define T_ 2048
#define E_ 1024
#define D_ 1024
#define H_ 4
#define DK_ 512
#define DV_ 512
#define C_ 10
#define FILT_ 100
#define KW_ 201
#define SCALING_ 2.0f
#define KEXT_ 32   // extension K-block holding [conv(10) | 1 | zeros]

typedef __bf16 bf16_t;
typedef __bf16 bf16x4 __attribute__((ext_vector_type(4)));
typedef __bf16 bf16x8 __attribute__((ext_vector_type(8)));
typedef float f32x4 __attribute__((ext_vector_type(4)));

__device__ __forceinline__ float fast_tanh(float x) {
    x = fminf(15.f, fmaxf(-15.f, x));
    float e = __expf(2.f * x);
    return (e - 1.f) / (e + 1.f);
}

__device__ __forceinline__ void gload16(const void* g, void* l) {
  __builtin_amdgcn_global_load_lds(
      (const __attribute__((address_space(1))) void*)g,
      (__attribute__((address_space(3))) void*)l, 16, 0, 0);
}

// ---------------- P1: fp32 -> bf16 elementwise (enc) ----------------
__global__ __launch_bounds__(256) void tobf16_kernel(
    const float* __restrict__ in, bf16_t* __restrict__ out) {
  size_t i = ((size_t)blockIdx.x * 256 + threadIdx.x) * 8;
  float4 a = *(const float4*)(in + i);
  float4 b = *(const float4*)(in + i + 4);
  bf16x8 o;
  o[0] = (bf16_t)a.x; o[1] = (bf16_t)a.y; o[2] = (bf16_t)a.z; o[3] = (bf16_t)a.w;
  o[4] = (bf16_t)b.x; o[5] = (bf16_t)b.y; o[6] = (bf16_t)b.z; o[7] = (bf16_t)b.w;
  *(bf16x8*)(out + i) = o;
}

// ---------------- P2: WkT[h,dk,e] = (bf16)Wk[h,e,dk] (tiled transpose) ----------------
__global__ __launch_bounds__(256) void wkt_kernel(
    const float* __restrict__ Wk, bf16_t* __restrict__ WkT) {
  __shared__ float t[32][33];
  int h = blockIdx.z;
  int dk0 = blockIdx.x * 32, e0 = blockIdx.y * 32;
  int x = threadIdx.x & 31, y0 = threadIdx.x >> 5;
  for (int yy = 0; yy < 32; yy += 8) {
    int y = y0 + yy;
    t[y][x] = Wk[((size_t)h * E_ + e0 + y) * DK_ + dk0 + x];
  }
  __syncthreads();
  for (int yy = 0; yy < 32; yy += 8) {
    int y = y0 + yy;
    WkT[((size_t)h * DK_ + dk0 + y) * E_ + e0 + x] = (bf16_t)t[x][y];
  }
}

// ---------------- K1: q[b,h,dk] += partial(dec_z[b,:] @ Wq[h,:,dk]) + bq ----------------
#define QSPLIT 8
__global__ __launch_bounds__(256) void qproj_kernel(
    const float* __restrict__ dec_z, const float* __restrict__ Wq,
    const float* __restrict__ bq, float* __restrict__ q) {
  int idx = blockIdx.x * 256 + threadIdx.x;   // B*H*DK
  int s = blockIdx.y;
  int dk = idx & (DK_ - 1);
  int h  = (idx >> 9) & (H_ - 1);
  int b  = idx >> 11;
  const int CH = D_ / QSPLIT;                 // 128
  const float* dz = dec_z + (size_t)b * D_ + s * CH;
  const float* w  = Wq + (size_t)h * D_ * DK_ + (size_t)(s * CH) * DK_ + dk;
  float acc = (s == 0) ? bq[h * DK_ + dk] : 0.f;
  for (int d = 0; d < CH; ++d) acc += dz[d] * w[(size_t)d * DK_];
  atomicAdd(q + idx, acc);
}

// ---------------- P3: transpose conv_w (H,C,K) -> (H,K,C) ----------------
__global__ __launch_bounds__(256) void cwt_kernel(
    const float* __restrict__ cw, float* __restrict__ cwT) {
  int idx = blockIdx.x * 256 + threadIdx.x;
  if (idx < H_ * C_ * KW_) {
    int k = idx % KW_;
    int c = (idx / KW_) % C_;
    int h = idx / (KW_ * C_);
    cwT[((size_t)h * KW_ + k) * C_ + c] = cw[idx];
  }
}

// ---------------- K2: conv -> convT[bh,t,0:32] = [conv_c(t) x10 | 1 | zeros] bf16 ----
__global__ __launch_bounds__(256) void conv_kernel(
    const float* __restrict__ att_prev, const float* __restrict__ cwT,
    bf16_t* __restrict__ convT) {
  int bh = blockIdx.y;                 // b*H + h
  int h  = bh & (H_ - 1);
  int t0 = blockIdx.x * 256;
  int tid = threadIdx.x;
  __shared__ float sh[256 + 2 * FILT_];
  const float* ap = att_prev + (size_t)bh * T_;
  for (int f = tid; f < 256 + 2 * FILT_; f += 256) {
    int t = t0 + f - FILT_;
    sh[f] = (t >= 0 && t < T_) ? ap[t] : 0.f;
  }
  __syncthreads();
  const float* wt = cwT + (size_t)h * KW_ * C_;
  float out[C_];
#pragma unroll
  for (int c = 0; c < C_; ++c) out[c] = 0.f;
  for (int k = 0; k < KW_; ++k) {
    float x = sh[tid + k];
    const float* wk = wt + k * C_;     // uniform address -> scalar loads
#pragma unroll
    for (int c = 0; c < C_; ++c) out[c] += wk[c] * x;
  }
  bf16_t* o = convT + ((size_t)bh * T_ + t0 + tid) * KEXT_;
#pragma unroll
  for (int c = 0; c < C_; ++c) o[c] = (bf16_t)out[c];
  o[C_] = (bf16_t)1.0f;
#pragma unroll
  for (int c = C_ + 1; c < KEXT_; ++c) o[c] = (bf16_t)0.0f;
}

// ---------------- K3: Bext[bh,dk,0:32] = [Watt_c(dk) x10 | q(bh,dk) | zeros] bf16 ----
__global__ __launch_bounds__(256) void bext_kernel(
    const float* __restrict__ Watt, const float* __restrict__ q,
    bf16_t* __restrict__ Bext) {
  int idx = blockIdx.x * 256 + threadIdx.x;  // B*H*DK
  int dk = idx & (DK_ - 1);
  int h = (idx >> 9) & (H_ - 1);
  bf16_t* o = Bext + (size_t)idx * KEXT_;
#pragma unroll
  for (int c = 0; c < C_; ++c) o[c] = (bf16_t)Watt[((size_t)h * C_ + c) * DK_ + dk];
  o[C_] = (bf16_t)q[idx];
#pragma unroll
  for (int c = C_ + 1; c < KEXT_; ++c) o[c] = (bf16_t)0.0f;
}

// ---------------- K4: MFMA e-kernel: e[bh,t] = sum_dk tanh(enc@Wk + loc + q)*gw -----
// 128x128 tile, BK=128 bf16 (64 KiB LDS), global_load_lds 16B, XOR-swizzled LDS,
// 4 waves x (4x4) 16x16x32 MFMAs. Grid: x=(h,dk) so A-tile sharers are adjacent.
#define WT 128
#define WN 128
#define WKB 128
__global__ __launch_bounds__(256) void e_mfma_kernel(
    const bf16_t* __restrict__ encb, const bf16_t* __restrict__ WkT,
    const bf16_t* __restrict__ convT, const bf16_t* __restrict__ Bext,
    const float* __restrict__ gw, float* __restrict__ e_out) {
  __shared__ bf16_t As[WT * WKB];   // 32 KiB
  __shared__ bf16_t Bs[WN * WKB];   // 32 KiB
  int tid = threadIdx.x;
  int wave = tid >> 6, lane = tid & 63;
  int xdk = blockIdx.x & 3, h = blockIdx.x >> 2;
  int b = blockIdx.z;
  int bh = b * H_ + h;
  int t0 = blockIdx.y * WT;
  int n0b = xdk * WN;
  const bf16_t* Ag = encb + ((size_t)b * T_ + t0) * E_;
  const bf16_t* Bg = WkT + ((size_t)h * DK_ + n0b) * E_;

  f32x4 acc[4][4] = {};

  int m0 = (wave & 1) * 64, n0 = (wave >> 1) * 64;
  int lr = lane & 15, lk = (lane >> 4) * 8;

  for (int e0 = 0; e0 < E_; e0 += WKB) {
    // stage 128x128 A and B tiles; LDS slot (r,cb) <- global colblock cb^(r&15)
#pragma unroll
    for (int j = 0; j < 8; ++j) {
      int s = tid + 256 * j;           // 0..2047
      int r = s >> 4, cbk = s & 15;
      int gc = (cbk ^ (r & 15)) * 8;
      gload16(Ag + (size_t)r * E_ + e0 + gc, As + r * WKB + cbk * 8);
      gload16(Bg + (size_t)r * E_ + e0 + gc, Bs + r * WKB + cbk * 8);
    }
    __syncthreads();
#pragma unroll
    for (int kk = 0; kk < WKB; kk += 32) {
      int CB = (kk + lk) >> 3;
      int sc = (CB ^ lr) << 3;        // swizzled col offset (row&15 == lr)
      bf16x8 af[4], bfv[4];
#pragma unroll
      for (int i = 0; i < 4; ++i) {
        af[i]  = *(const bf16x8*)(As + (m0 + i * 16 + lr) * WKB + sc);
        bfv[i] = *(const bf16x8*)(Bs + (n0 + i * 16 + lr) * WKB + sc);
      }
#pragma unroll
      for (int i = 0; i < 4; ++i)
#pragma unroll
        for (int j = 0; j < 4; ++j)
          acc[i][j] = __builtin_amdgcn_mfma_f32_16x16x32_bf16(
              af[i], bfv[j], acc[i][j], 0, 0, 0);
    }
    __syncthreads();
  }

  // extension K-block (32 wide): A <- convT rows, B <- Bext rows (no swizzle)
  {
    const bf16_t* Ag2 = convT + ((size_t)bh * T_ + t0) * KEXT_;
    const bf16_t* Bg2 = Bext + ((size_t)bh * DK_ + n0b) * KEXT_;
    int srow2 = wave * 32 + (lane >> 2);   // 16 rows per instr per wave
    int scol2 = (lane & 3) * 8;
#pragma unroll
    for (int j = 0; j < 2; ++j) {
      int r = srow2 + j * 16;
      gload16(Ag2 + (size_t)r * KEXT_ + scol2, As + r * KEXT_ + scol2);
      gload16(Bg2 + (size_t)r * KEXT_ + scol2, Bs + r * KEXT_ + scol2);
    }
    __syncthreads();
    bf16x8 af[4], bfv[4];
#pragma unroll
    for (int i = 0; i < 4; ++i) {
      af[i]  = *(const bf16x8*)(As + (m0 + i * 16 + lr) * KEXT_ + lk);
      bfv[i] = *(const bf16x8*)(Bs + (n0 + i * 16 + lr) * KEXT_ + lk);
    }
#pragma unroll
    for (int i = 0; i < 4; ++i)
#pragma unroll
      for (int j = 0; j < 4; ++j)
        acc[i][j] = __builtin_amdgcn_mfma_f32_16x16x32_bf16(
            af[i], bfv[j], acc[i][j], 0, 0, 0);
  }

  // epilogue: e[t] partial = sum over this block's 128 dk cols of tanh(acc)*gw
  float gwv[4];
#pragma unroll
  for (int j = 0; j < 4; ++j)
    gwv[j] = gw[(size_t)h * DK_ + n0b + n0 + j * 16 + lr];
  int rquad = (lane >> 4) * 4;
#pragma unroll
  for (int i = 0; i < 4; ++i) {
#pragma unroll
    for (int r = 0; r < 4; ++r) {
      int row = m0 + i * 16 + rquad + r;
      float part = 0.f;
#pragma unroll
      for (int j = 0; j < 4; ++j)
        part += fast_tanh(acc[i][j][r]) * gwv[j];
#pragma unroll
      for (int off = 8; off > 0; off >>= 1) part += __shfl_xor(part, off, 64);
      if (lr == 0) atomicAdd(e_out + (size_t)bh * T_ + t0 + row, part);
    }
  }
}

// ---------------- K5: w = softmax(SCALING*(e+gb)) with length mask ----------------
__global__ __launch_bounds__(256) void softmax_kernel(
    const float* __restrict__ e, const float* __restrict__ gb,
    const int* __restrict__ len, float* __restrict__ w_out) {
  int bh = blockIdx.x;
  int b = bh >> 2, h = bh & 3;
  int tid = threadIdx.x;
  int L = len[b];
  const float* er = e + (size_t)bh * T_;
  float* wr = w_out + (size_t)bh * T_;
  float gbh = gb[h];
  __shared__ float redA[4], redB[4];
  float mx = -1e30f;
  for (int t = tid; t < T_; t += 256)
    if (t < L) mx = fmaxf(mx, er[t] + gbh);
#pragma unroll
  for (int off = 32; off > 0; off >>= 1) mx = fmaxf(mx, __shfl_xor(mx, off, 64));
  if ((tid & 63) == 0) redA[tid >> 6] = mx;
  __syncthreads();
  mx = fmaxf(fmaxf(redA[0], redA[1]), fmaxf(redA[2], redA[3]));
  float sum = 0.f;
  for (int t = tid; t < T_; t += 256)
    if (t < L) sum += __expf(SCALING_ * ((er[t] + gbh) - mx));
#pragma unroll
  for (int off = 32; off > 0; off >>= 1) sum += __shfl_xor(sum, off, 64);
  if ((tid & 63) == 0) redB[tid >> 6] = sum;
  __syncthreads();
  sum = redB[0] + redB[1] + redB[2] + redB[3];
  float inv = 1.f / sum;
  for (int t = tid; t < T_; t += 256)
    wr[t] = (t < L) ? __expf(SCALING_ * ((er[t] + gbh) - mx)) * inv : 0.f;
}

// ---------------- K6: we[b,h,e] += sum_t w[b,h,t] * enc_bf16[b,t,e] ----------------
#define TCH 256
__global__ __launch_bounds__(256) void wenc_kernel(
    const bf16_t* __restrict__ encb, const float* __restrict__ w,
    const int* __restrict__ len, float* __restrict__ we) {
  int b = blockIdx.y;
  int t0 = blockIdx.x * TCH;
  int L = len[b];
  if (t0 >= L) return;
  int tid = threadIdx.x;
  __shared__ float wS[H_ * TCH];
  const float* wb = w + (size_t)b * H_ * T_;
#pragma unroll
  for (int l = 0; l < H_; ++l)
    wS[l * TCH + tid] = wb[(size_t)l * T_ + t0 + tid];
  __syncthreads();
  const bf16_t* eb = encb + (size_t)b * T_ * E_;
  int tmax = min(TCH, L - t0);
  float4 a0 = {0.f, 0.f, 0.f, 0.f}, a1 = a0, a2 = a0, a3 = a0;
  for (int tt = 0; tt < tmax; ++tt) {
    bf16x4 xb = *(const bf16x4*)(eb + (size_t)(t0 + tt) * E_ + tid * 4);
    float4 x = {(float)xb[0], (float)xb[1], (float)xb[2], (float)xb[3]};
    float w0 = wS[tt], w1 = wS[TCH + tt], w2 = wS[2 * TCH + tt], w3 = wS[3 * TCH + tt];
    a0.x += w0 * x.x; a0.y += w0 * x.y; a0.z += w0 * x.z; a0.w += w0 * x.w;
    a1.x += w1 * x.x; a1.y += w1 * x.y; a1.z += w1 * x.z; a1.w += w1 * x.w;
    a2.x += w2 * x.x; a2.y += w2 * x.y; a2.z += w2 * x.z; a2.w += w2 * x.w;
    a3.x += w3 * x.x; a3.y += w3 * x.y; a3.z += w3 * x.z; a3.w += w3 * x.w;
  }
  float* p = we + (size_t)b * H_ * E_ + tid * 4;
  atomicAdd(p + 0 * E_ + 0, a0.x); atomicAdd(p + 0 * E_ + 1, a0.y);
  atomicAdd(p + 0 * E_ + 2, a0.z); atomicAdd(p + 0 * E_ + 3, a0.w);
  atomicAdd(p + 1 * E_ + 0, a1.x); atomicAdd(p + 1 * E_ + 1, a1.y);
  atomicAdd(p + 1 * E_ + 2, a1.z); atomicAdd(p + 1 * E_ + 3, a1.w);
  atomicAdd(p + 2 * E_ + 0, a2.x); atomicAdd(p + 2 * E_ + 1, a2.y);
  atomicAdd(p + 2 * E_ + 2, a2.z); atomicAdd(p + 2 * E_ + 3, a2.w);
  atomicAdd(p + 3 * E_ + 0, a3.x); atomicAdd(p + 3 * E_ + 1, a3.y);
  atomicAdd(p + 3 * E_ + 2, a3.z); atomicAdd(p + 3 * E_ + 3, a3.w);
}

// ---------------- K7a: ctx[b,h,dv] += partial(we[b,h,:] @ Wv[h,:,dv]) ----------------
#define CSPLIT 8
__global__ __launch_bounds__(256) void ctx_kernel(
    const float* __restrict__ we, const float* __restrict__ Wv,
    float* __restrict__ ctx) {
  int idx = blockIdx.x * 256 + threadIdx.x;  // B*H*DV
  int s = blockIdx.y;
  int dv = idx & (DV_ - 1);
  int bh = idx >> 9;
  int h = bh & 3;
  const int CH = E_ / CSPLIT;                // 128
  const float* weh = we + (size_t)bh * E_ + s * CH;
  const float* wvp = Wv + (size_t)h * E_ * DV_ + (size_t)(s * CH) * DV_ + dv;
  float acc = 0.f;
  for (int e = 0; e < CH; ++e) acc += weh[e] * wvp[(size_t)e * DV_];
  atomicAdd(ctx + idx, acc);
}

// ---------------- K7b: c[b,eo] += partial(ctx_flat[b,:] @ Wo[:,eo]) ----------------
#define OSPLIT 8
__global__ __launch_bounds__(256) void out_kernel(
    const float* __restrict__ ctx, const float* __restrict__ Wo,
    float* __restrict__ c_out) {
  int eo = blockIdx.x * 256 + threadIdx.x;
  int b = blockIdx.y;
  int s = blockIdx.z;
  const int CH = (H_ * DV_) / OSPLIT;        // 256
  const float* cb = ctx + (size_t)b * (H_ * DV_) + s * CH;
  const float* wp = Wo + (size_t)(s * CH) * E_ + eo;
  float acc = 0.f;
  for (int i = 0; i < CH; ++i) acc += cb[i] * wp[(size_t)i * E_];
  atomicAdd(c_out + (size_t)b * E_ + eo, acc);
}

extern "C" void kernel_launch(void* const* d_in, const int* in_sizes, int n_in,
                              void* d_out, int out_size, void* d_ws, size_t ws_size,
                              hipStream_t stream) {
  const float* enc  = (const float*)d_in[0];
  const int*   len  = (const int*)d_in[1];
  const float* decz = (const float*)d_in[2];
  const float* attp = (const float*)d_in[3];
  const float* Wq   = (const float*)d_in[4];
  const float* bq   = (const float*)d_in[5];
  const float* Wk   = (const float*)d_in[6];
  const float* Wv   = (const float*)d_in[7];
  const float* gw   = (const float*)d_in[8];
  const float* gb   = (const float*)d_in[9];
  const float* cw   = (const float*)d_in[10];
  const float* Watt = (const float*)d_in[11];
  const float* Wo   = (const float*)d_in[12];

  float* c_out = (float*)d_out;                       // (B,E)
  float* w_out = c_out + (size_t)B_ * E_;             // (B,H,T)

  // workspace carve-up: [q | e | we | ctx] contiguous (single memset), then rest
  float* q    = (float*)d_ws;                                   // B*H*DK
  float* e    = q   + (size_t)B_ * H_ * DK_;                    // B*H*T
  float* we   = e   + (size_t)B_ * H_ * T_;                     // B*H*E
  float* ctx  = we  + (size_t)B_ * H_ * E_;                     // B*H*DV
  float* cwT  = ctx + (size_t)B_ * H_ * DV_;                    // H*KW*C
  bf16_t* encb16 = (bf16_t*)(cwT + (size_t)H_ * KW_ * C_ + 64); // B*T*E
  bf16_t* WkT    = encb16 + (size_t)B_ * T_ * E_;               // H*DK*E
  bf16_t* convT  = WkT + (size_t)H_ * DK_ * E_;                 // B*H*T*KEXT
  bf16_t* Bext   = convT + (size_t)B_ * H_ * T_ * KEXT_;        // B*H*DK*KEXT

  size_t zero_floats = (size_t)B_ * H_ * (DK_ + T_ + E_ + DV_);
  hipMemsetAsync(q, 0, zero_floats * sizeof(float), stream);
  hipMemsetAsync(c_out, 0, (size_t)B_ * E_ * sizeof(float), stream);

  tobf16_kernel<<<(size_t)B_ * T_ * E_ / 8 / 256, 256, 0, stream>>>(enc, encb16);
  wkt_kernel<<<dim3(DK_ / 32, E_ / 32, H_), 256, 0, stream>>>(Wk, WkT);
  qproj_kernel<<<dim3(B_ * H_ * DK_ / 256, QSPLIT), 256, 0, stream>>>(decz, Wq, bq, q);
  cwt_kernel<<<(H_ * C_ * KW_ + 255) / 256, 256, 0, stream>>>(cw, cwT);
  conv_kernel<<<dim3(T_ / 256, B_ * H_), 256, 0, stream>>>(attp, cwT, convT);
  bext_kernel<<<B_ * H_ * DK_ / 256, 256, 0, stream>>>(Watt, q, Bext);
  e_mfma_kernel<<<dim3((DK_ / WN) * H_, T_ / WT, B_), 256, 0, stream>>>(
      encb16, WkT, convT, Bext, gw, e);
  softmax_kernel<<<B_ * H_, 256, 0, stream>>>(e, gb, len, w_out);
  wenc_kernel<<<dim3(T_ / TCH, B_), 256, 0, stream>>>(encb16, w_out, len, we);
  ctx_kernel<<<dim3(B_ * H_ * DV_ / 256, CSPLIT), 256, 0, stream>>>(we, Wv, ctx);
  out_kernel<<<dim3(E_ / 256, B_, OSPLIT), 256, 0, stream>>>(ctx, Wo, c_out);
}